// Round 1
// baseline (171.272 us; speedup 1.0000x reference)
//
#include <hip/hip_runtime.h>
#include <hip/hip_bf16.h>
#include <stdint.h>

// Problem constants (B=8, S=2048, E=1024, H=128, DK=8)
#define M_DIM 16384   // B*S
#define N_DIM 1024    // E (output features)
#define K_DIM 1024    // E (reduction)

typedef __attribute__((ext_vector_type(8))) short short8;
typedef __attribute__((ext_vector_type(4))) float f32x4;

// async global->LDS, 16B per lane. LDS dest must be wave-uniform base + lane*16.
#define GLD_LDS(g, l) __builtin_amdgcn_global_load_lds( \
    (const __attribute__((address_space(1))) unsigned int*)(g), \
    (__attribute__((address_space(3))) unsigned int*)(l), 16, 0, 0)

__device__ __forceinline__ unsigned short f2bf(float f) {
  union { float f; unsigned int u; } v;
  v.f = f;
  unsigned int u = v.u + 0x7FFFu + ((v.u >> 16) & 1u);  // RNE
  return (unsigned short)(u >> 16);
}

// A_bf16[m,k] = bf16(cos(x[m,k] + theta[k % 1024])); 8 elems/thread.
__global__ __launch_bounds__(256) void prep_a(const float* __restrict__ x,
                                              const float* __restrict__ theta,
                                              unsigned short* __restrict__ A) {
  const long i = ((long)blockIdx.x * 256 + threadIdx.x) * 8;
  const int k = (int)(i & (K_DIM - 1));  // row length = 1024, 8-aligned so k..k+7 in range
  float4 x0 = *(const float4*)(x + i);
  float4 x1 = *(const float4*)(x + i + 4);
  float4 t0 = *(const float4*)(theta + k);
  float4 t1 = *(const float4*)(theta + k + 4);
  union { unsigned short s[8]; short8 v; } o;
  o.s[0] = f2bf(__cosf(x0.x + t0.x));
  o.s[1] = f2bf(__cosf(x0.y + t0.y));
  o.s[2] = f2bf(__cosf(x0.z + t0.z));
  o.s[3] = f2bf(__cosf(x0.w + t0.w));
  o.s[4] = f2bf(__cosf(x1.x + t1.x));
  o.s[5] = f2bf(__cosf(x1.y + t1.y));
  o.s[6] = f2bf(__cosf(x1.z + t1.z));
  o.s[7] = f2bf(__cosf(x1.w + t1.w));
  *(short8*)(A + i) = o.v;
}

// W_bf16[n,k] = bf16(W[n,k]); 8 elems/thread.
__global__ __launch_bounds__(256) void prep_w(const float* __restrict__ W,
                                              unsigned short* __restrict__ Wb) {
  const long i = ((long)blockIdx.x * 256 + threadIdx.x) * 8;
  float4 w0 = *(const float4*)(W + i);
  float4 w1 = *(const float4*)(W + i + 4);
  union { unsigned short s[8]; short8 v; } o;
  o.s[0] = f2bf(w0.x); o.s[1] = f2bf(w0.y); o.s[2] = f2bf(w0.z); o.s[3] = f2bf(w0.w);
  o.s[4] = f2bf(w1.x); o.s[5] = f2bf(w1.y); o.s[6] = f2bf(w1.z); o.s[7] = f2bf(w1.w);
  *(short8*)(Wb + i) = o.v;
}

// C[m,n] = sum_k A[m,k]*Bt[n,k] + bias[n].  A:[M,K] bf16, Bt:[N,K] bf16, C:[M,N] f32.
// m97-style: 128x128 tile, BK=64, 4 waves of 64x64, 16x16x32 bf16 MFMA,
// global_load_lds width=16 staging, single-buffered 2-barrier K-loop.
__global__ __launch_bounds__(256) void gemm_bt(const unsigned short* __restrict__ A,
                                               const unsigned short* __restrict__ Bt,
                                               const float* __restrict__ bias,
                                               float* __restrict__ C) {
  constexpr int BM = 128, BN = 128, BK = 64;
  __shared__ unsigned short As[BM * BK];  // 16 KB, row-major [128][64], no pad
  __shared__ unsigned short Bs[BN * BK];  // 16 KB
  const int tid = threadIdx.x;
  const int m0 = blockIdx.y * BM;
  const int n0 = blockIdx.x * BN;
  const int lane = tid & 63;
  const int wave = tid >> 6;
  const int wm = (wave >> 1) * 64;  // wave tile origin in M
  const int wn = (wave & 1) * 64;   // wave tile origin in N

  f32x4 acc[4][4] = {};

  // Staging: chunk c = i*256 + tid covers tile row c>>3, col (c&7)*8; LDS off = c*16B.
  const int srow = tid >> 3;       // 0..31
  const int scol = (tid & 7) * 8;  // 0,8,..,56
  const unsigned short* Ag = A + (long)(m0 + srow) * K_DIM + scol;
  const unsigned short* Bg = Bt + (long)(n0 + srow) * K_DIM + scol;
  unsigned short* Asd = As + tid * 8;
  unsigned short* Bsd = Bs + tid * 8;

  for (int k0 = 0; k0 < K_DIM; k0 += BK) {
    __syncthreads();  // all waves done reading previous tile
#pragma unroll
    for (int i = 0; i < 4; ++i)
      GLD_LDS(Ag + (long)i * 32 * K_DIM, Asd + i * 2048);
#pragma unroll
    for (int i = 0; i < 4; ++i)
      GLD_LDS(Bg + (long)i * 32 * K_DIM, Bsd + i * 2048);
    Ag += BK;
    Bg += BK;
    __syncthreads();  // compiler emits vmcnt(0) drain -> LDS ready

#pragma unroll
    for (int s = 0; s < 2; ++s) {
      const int kr = s * 32 + (lane >> 4) * 8;
      short8 af[4], bf[4];
#pragma unroll
      for (int i = 0; i < 4; ++i)
        af[i] = *(const short8*)(As + (wm + i * 16 + (lane & 15)) * BK + kr);
#pragma unroll
      for (int j = 0; j < 4; ++j)
        bf[j] = *(const short8*)(Bs + (wn + j * 16 + (lane & 15)) * BK + kr);
#pragma unroll
      for (int i = 0; i < 4; ++i)
#pragma unroll
        for (int j = 0; j < 4; ++j)
          acc[i][j] = __builtin_amdgcn_mfma_f32_16x16x32_bf16(af[i], bf[j], acc[i][j], 0, 0, 0);
    }
  }

  // Epilogue: D[row=(lane>>4)*4+r][col=lane&15] per 16x16 frag (m89-verified layout).
  const int cn = lane & 15;
  const int rq = (lane >> 4) * 4;
#pragma unroll
  for (int j = 0; j < 4; ++j) {
    const int n = n0 + wn + j * 16 + cn;
    const float bv = bias[n];
#pragma unroll
    for (int i = 0; i < 4; ++i) {
      const long mb = (long)(m0 + wm + i * 16 + rq) * N_DIM + n;
#pragma unroll
      for (int r = 0; r < 4; ++r)
        C[mb + (long)r * N_DIM] = acc[i][j][r] + bv;
    }
  }
}

extern "C" void kernel_launch(void* const* d_in, const int* in_sizes, int n_in,
                              void* d_out, int out_size, void* d_ws, size_t ws_size,
                              hipStream_t stream) {
  const float* x = (const float*)d_in[0];      // [8,2048,1024]
  const float* theta = (const float*)d_in[1];  // [128,8] -> flat 1024
  const float* W = (const float*)d_in[2];      // [1024,1024]
  const float* b = (const float*)d_in[3];      // [1024]
  float* out = (float*)d_out;                  // [8,2048,1024] f32

  unsigned short* Abf = (unsigned short*)d_ws;                   // 33.5 MB
  unsigned short* Wbf = Abf + (size_t)M_DIM * K_DIM;             // +2 MB

  hipLaunchKernelGGL(prep_a, dim3((M_DIM * K_DIM) / (256 * 8)), dim3(256), 0, stream,
                     x, theta, Abf);
  hipLaunchKernelGGL(prep_w, dim3((N_DIM * K_DIM) / (256 * 8)), dim3(256), 0, stream,
                     W, Wbf);
  hipLaunchKernelGGL(gemm_bt, dim3(N_DIM / 128, M_DIM / 128), dim3(256), 0, stream,
                     Abf, Wbf, b, out);
}

// Round 2
// 165.743 us; speedup vs baseline: 1.0334x; 1.0334x over previous
//
#include <hip/hip_runtime.h>
#include <hip/hip_bf16.h>
#include <stdint.h>

// Problem constants (B=8, S=2048, E=1024, H=128, DK=8)
#define M_DIM 16384   // B*S
#define N_DIM 1024    // E (output features)
#define K_DIM 1024    // E (reduction)

typedef __attribute__((ext_vector_type(8))) short short8;
typedef __attribute__((ext_vector_type(4))) float f32x4;

// async global->LDS, 16B per lane. LDS dest must be wave-uniform base + lane*16.
#define GLD_LDS(g, l) __builtin_amdgcn_global_load_lds( \
    (const __attribute__((address_space(1))) unsigned int*)(g), \
    (__attribute__((address_space(3))) unsigned int*)(l), 16, 0, 0)

__device__ __forceinline__ unsigned short f2bf(float f) {
  union { float f; unsigned int u; } v;
  v.f = f;
  unsigned int u = v.u + 0x7FFFu + ((v.u >> 16) & 1u);  // RNE
  return (unsigned short)(u >> 16);
}

// A_bf16[m,k] = bf16(cos(x[m,k] + theta[k % 1024])); 8 elems/thread.
__global__ __launch_bounds__(256) void prep_a(const float* __restrict__ x,
                                              const float* __restrict__ theta,
                                              unsigned short* __restrict__ A) {
  const long i = ((long)blockIdx.x * 256 + threadIdx.x) * 8;
  const int k = (int)(i & (K_DIM - 1));  // row length = 1024, 8-aligned so k..k+7 in range
  float4 x0 = *(const float4*)(x + i);
  float4 x1 = *(const float4*)(x + i + 4);
  float4 t0 = *(const float4*)(theta + k);
  float4 t1 = *(const float4*)(theta + k + 4);
  union { unsigned short s[8]; short8 v; } o;
  o.s[0] = f2bf(__cosf(x0.x + t0.x));
  o.s[1] = f2bf(__cosf(x0.y + t0.y));
  o.s[2] = f2bf(__cosf(x0.z + t0.z));
  o.s[3] = f2bf(__cosf(x0.w + t0.w));
  o.s[4] = f2bf(__cosf(x1.x + t1.x));
  o.s[5] = f2bf(__cosf(x1.y + t1.y));
  o.s[6] = f2bf(__cosf(x1.z + t1.z));
  o.s[7] = f2bf(__cosf(x1.w + t1.w));
  *(short8*)(A + i) = o.v;
}

// W_bf16[n,k] = bf16(W[n,k]); 8 elems/thread.
__global__ __launch_bounds__(256) void prep_w(const float* __restrict__ W,
                                              unsigned short* __restrict__ Wb) {
  const long i = ((long)blockIdx.x * 256 + threadIdx.x) * 8;
  float4 w0 = *(const float4*)(W + i);
  float4 w1 = *(const float4*)(W + i + 4);
  union { unsigned short s[8]; short8 v; } o;
  o.s[0] = f2bf(w0.x); o.s[1] = f2bf(w0.y); o.s[2] = f2bf(w0.z); o.s[3] = f2bf(w0.w);
  o.s[4] = f2bf(w1.x); o.s[5] = f2bf(w1.y); o.s[6] = f2bf(w1.z); o.s[7] = f2bf(w1.w);
  *(short8*)(Wb + i) = o.v;
}

// C[m,n] = sum_k A[m,k]*Bt[n,k] + bias[n].  A:[M,K] bf16, Bt:[N,K] bf16, C:[M,N] f32.
// 128x128 tile, BK=64, 4 waves of 64x64, 16x16x32 bf16 MFMA, global_load_lds
// width=16 staging. LDS bank-conflict fix: XOR chunk swizzle — 16B chunk
// (row, c) of the tile lives at LDS slot (row, c ^ (row&7)). Staging inverts
// the swizzle on the SOURCE address (dest must stay wave-uniform + lane*16);
// fragment reads apply the same XOR. Breaks the 16-way same-bank pattern of
// row-stride-128B reads into 8 bank-quads x 2 lanes (2-way = free, m136).
__global__ __launch_bounds__(256) void gemm_bt(const unsigned short* __restrict__ A,
                                               const unsigned short* __restrict__ Bt,
                                               const float* __restrict__ bias,
                                               float* __restrict__ C) {
  constexpr int BM = 128, BN = 128, BK = 64;
  __shared__ unsigned short As[BM * BK];  // 16 KB, row-major [128][64], chunk-swizzled
  __shared__ unsigned short Bs[BN * BK];  // 16 KB
  const int tid = threadIdx.x;
  const int m0 = blockIdx.y * BM;
  const int n0 = blockIdx.x * BN;
  const int lane = tid & 63;
  const int wave = tid >> 6;
  const int wm = (wave >> 1) * 64;  // wave tile origin in M
  const int wn = (wave & 1) * 64;   // wave tile origin in N

  f32x4 acc[4][4] = {};

  // Staging: LDS slot d = i*256 + tid holds global chunk (row = d>>3,
  // c = (d&7) ^ (row&7)). Note (d>>3)&7 == (tid>>3)&7 for all i (i*256 adds
  // multiples of 32 rows), so the source column is loop-invariant.
  const int srow = tid >> 3;                         // 0..31
  const int scol = ((tid & 7) ^ (srow & 7)) * 8;     // swizzled source column
  const unsigned short* Ag = A + (long)(m0 + srow) * K_DIM + scol;
  const unsigned short* Bg = Bt + (long)(n0 + srow) * K_DIM + scol;
  unsigned short* Asd = As + tid * 8;
  unsigned short* Bsd = Bs + tid * 8;

  for (int k0 = 0; k0 < K_DIM; k0 += BK) {
    __syncthreads();  // all waves done reading previous tile
#pragma unroll
    for (int i = 0; i < 4; ++i)
      GLD_LDS(Ag + (long)i * 32 * K_DIM, Asd + i * 2048);
#pragma unroll
    for (int i = 0; i < 4; ++i)
      GLD_LDS(Bg + (long)i * 32 * K_DIM, Bsd + i * 2048);
    Ag += BK;
    Bg += BK;
    __syncthreads();  // vmcnt(0) drain -> LDS ready

#pragma unroll
    for (int s = 0; s < 2; ++s) {
      const int kr = s * 32 + (lane >> 4) * 8;
      const int c = kr >> 3;  // chunk column 0..7
      short8 af[4], bf[4];
#pragma unroll
      for (int i = 0; i < 4; ++i) {
        const int r = wm + i * 16 + (lane & 15);
        af[i] = *(const short8*)(As + r * BK + (c ^ (r & 7)) * 8);
      }
#pragma unroll
      for (int j = 0; j < 4; ++j) {
        const int r = wn + j * 16 + (lane & 15);
        bf[j] = *(const short8*)(Bs + r * BK + (c ^ (r & 7)) * 8);
      }
#pragma unroll
      for (int i = 0; i < 4; ++i)
#pragma unroll
        for (int j = 0; j < 4; ++j)
          acc[i][j] = __builtin_amdgcn_mfma_f32_16x16x32_bf16(af[i], bf[j], acc[i][j], 0, 0, 0);
    }
  }

  // Epilogue: D[row=(lane>>4)*4+r][col=lane&15] per 16x16 frag (m89-verified layout).
  const int cn = lane & 15;
  const int rq = (lane >> 4) * 4;
#pragma unroll
  for (int j = 0; j < 4; ++j) {
    const int n = n0 + wn + j * 16 + cn;
    const float bv = bias[n];
#pragma unroll
    for (int i = 0; i < 4; ++i) {
      const long mb = (long)(m0 + wm + i * 16 + rq) * N_DIM + n;
#pragma unroll
      for (int r = 0; r < 4; ++r)
        C[mb + (long)r * N_DIM] = acc[i][j][r] + bv;
    }
  }
}

extern "C" void kernel_launch(void* const* d_in, const int* in_sizes, int n_in,
                              void* d_out, int out_size, void* d_ws, size_t ws_size,
                              hipStream_t stream) {
  const float* x = (const float*)d_in[0];      // [8,2048,1024]
  const float* theta = (const float*)d_in[1];  // [128,8] -> flat 1024
  const float* W = (const float*)d_in[2];      // [1024,1024]
  const float* b = (const float*)d_in[3];      // [1024]
  float* out = (float*)d_out;                  // [8,2048,1024] f32

  unsigned short* Abf = (unsigned short*)d_ws;                   // 33.5 MB
  unsigned short* Wbf = Abf + (size_t)M_DIM * K_DIM;             // +2 MB

  hipLaunchKernelGGL(prep_a, dim3((M_DIM * K_DIM) / (256 * 8)), dim3(256), 0, stream,
                     x, theta, Abf);
  hipLaunchKernelGGL(prep_w, dim3((N_DIM * K_DIM) / (256 * 8)), dim3(256), 0, stream,
                     W, Wbf);
  hipLaunchKernelGGL(gemm_bt, dim3(N_DIM / 128, M_DIM / 128), dim3(256), 0, stream,
                     Abf, Wbf, b, out);
}

// Round 3
// 153.904 us; speedup vs baseline: 1.1128x; 1.0769x over previous
//
#include <hip/hip_runtime.h>
#include <hip/hip_bf16.h>
#include <stdint.h>

// Problem constants (B=8, S=2048, E=1024, H=128, DK=8)
#define M_DIM 16384   // B*S
#define N_DIM 1024    // E (output features)
#define K_DIM 1024    // E (reduction)

typedef __attribute__((ext_vector_type(8))) short short8;
typedef __attribute__((ext_vector_type(4))) float f32x4;

// async global->LDS, 16B per lane. LDS dest must be wave-uniform base + lane*16.
#define GLD_LDS(g, l) __builtin_amdgcn_global_load_lds( \
    (const __attribute__((address_space(1))) unsigned int*)(g), \
    (__attribute__((address_space(3))) unsigned int*)(l), 16, 0, 0)

__device__ __forceinline__ unsigned short f2bf(float f) {
  union { float f; unsigned int u; } v;
  v.f = f;
  unsigned int u = v.u + 0x7FFFu + ((v.u >> 16) & 1u);  // RNE
  return (unsigned short)(u >> 16);
}

// Fused prep: blocks [0, 8192) -> A_bf16[m,k] = bf16(cos(x[m,k]+theta[k]));
//             blocks [8192, 8704) -> W_bf16 cast. 8 elems/thread, all 16B I/O.
#define PREP_A_BLOCKS (M_DIM * K_DIM / (256 * 8))   // 8192
#define PREP_W_BLOCKS (N_DIM * K_DIM / (256 * 8))   // 512
__global__ __launch_bounds__(256) void prep_all(const float* __restrict__ x,
                                                const float* __restrict__ theta,
                                                const float* __restrict__ W,
                                                unsigned short* __restrict__ A,
                                                unsigned short* __restrict__ Wb) {
  if (blockIdx.x < PREP_A_BLOCKS) {
    const long i = ((long)blockIdx.x * 256 + threadIdx.x) * 8;
    const int k = (int)(i & (K_DIM - 1));
    float4 x0 = *(const float4*)(x + i);
    float4 x1 = *(const float4*)(x + i + 4);
    float4 t0 = *(const float4*)(theta + k);
    float4 t1 = *(const float4*)(theta + k + 4);
    union { unsigned short s[8]; short8 v; } o;
    o.s[0] = f2bf(__cosf(x0.x + t0.x));
    o.s[1] = f2bf(__cosf(x0.y + t0.y));
    o.s[2] = f2bf(__cosf(x0.z + t0.z));
    o.s[3] = f2bf(__cosf(x0.w + t0.w));
    o.s[4] = f2bf(__cosf(x1.x + t1.x));
    o.s[5] = f2bf(__cosf(x1.y + t1.y));
    o.s[6] = f2bf(__cosf(x1.z + t1.z));
    o.s[7] = f2bf(__cosf(x1.w + t1.w));
    *(short8*)(A + i) = o.v;
  } else {
    const long i = ((long)(blockIdx.x - PREP_A_BLOCKS) * 256 + threadIdx.x) * 8;
    float4 w0 = *(const float4*)(W + i);
    float4 w1 = *(const float4*)(W + i + 4);
    union { unsigned short s[8]; short8 v; } o;
    o.s[0] = f2bf(w0.x); o.s[1] = f2bf(w0.y); o.s[2] = f2bf(w0.z); o.s[3] = f2bf(w0.w);
    o.s[4] = f2bf(w1.x); o.s[5] = f2bf(w1.y); o.s[6] = f2bf(w1.z); o.s[7] = f2bf(w1.w);
    *(short8*)(Wb + i) = o.v;
  }
}

// C[m,n] = sum_k A[m,k]*Bt[n,k] + bias[n].  A:[M,K] bf16, Bt:[N,K] bf16, C:[M,N] f32.
// 128x128 tile, BK=64, 4 waves of 64x64, 16x16x32 bf16 MFMA, global_load_lds
// width=16 staging, XOR chunk swizzle (conflict-free, verified r2: conflicts=0).
// XCD-aware remap: dispatch round-robins linear id across 8 XCDs, so L&7 ~ XCD.
// Map XCD c to a contiguous band of 16 A-row-tiles (by = c*16 + L/64, bx =
// (L>>3)&7, bijective) -> each A-tile is L2-filled on ~1 XCD instead of ~4
// (r2: FETCH 133 MB vs 37 MB ideal = cross-XCD A re-fetch).
__global__ __launch_bounds__(256) void gemm_bt(const unsigned short* __restrict__ A,
                                               const unsigned short* __restrict__ Bt,
                                               const float* __restrict__ bias,
                                               float* __restrict__ C) {
  constexpr int BM = 128, BN = 128, BK = 64;
  __shared__ unsigned short As[BM * BK];  // 16 KB
  __shared__ unsigned short Bs[BN * BK];  // 16 KB
  const int tid = threadIdx.x;

  const int L = blockIdx.y * 8 + blockIdx.x;  // linear dispatch id
  const int bx = (L >> 3) & 7;                // N-tile 0..7
  const int by = (L & 7) * 16 + (L >> 6);     // M-tile 0..127, banded per XCD
  const int m0 = by * BM;
  const int n0 = bx * BN;

  const int lane = tid & 63;
  const int wave = tid >> 6;
  const int wm = (wave >> 1) * 64;  // wave tile origin in M
  const int wn = (wave & 1) * 64;   // wave tile origin in N

  f32x4 acc[4][4] = {};

  // Staging: LDS slot d = i*256 + tid holds global chunk (row = d>>3,
  // c = (d&7) ^ (row&7)); (d>>3)&7 == (tid>>3)&7 for all i.
  const int srow = tid >> 3;                         // 0..31
  const int scol = ((tid & 7) ^ (srow & 7)) * 8;     // swizzled source column
  const unsigned short* Ag = A + (long)(m0 + srow) * K_DIM + scol;
  const unsigned short* Bg = Bt + (long)(n0 + srow) * K_DIM + scol;
  unsigned short* Asd = As + tid * 8;
  unsigned short* Bsd = Bs + tid * 8;

  for (int k0 = 0; k0 < K_DIM; k0 += BK) {
    __syncthreads();  // all waves done reading previous tile
#pragma unroll
    for (int i = 0; i < 4; ++i)
      GLD_LDS(Ag + (long)i * 32 * K_DIM, Asd + i * 2048);
#pragma unroll
    for (int i = 0; i < 4; ++i)
      GLD_LDS(Bg + (long)i * 32 * K_DIM, Bsd + i * 2048);
    Ag += BK;
    Bg += BK;
    __syncthreads();  // vmcnt(0) drain -> LDS ready

#pragma unroll
    for (int s = 0; s < 2; ++s) {
      const int kr = s * 32 + (lane >> 4) * 8;
      const int c = kr >> 3;  // chunk column 0..7
      short8 af[4], bf[4];
#pragma unroll
      for (int i = 0; i < 4; ++i) {
        const int r = wm + i * 16 + (lane & 15);
        af[i] = *(const short8*)(As + r * BK + (c ^ (r & 7)) * 8);
      }
#pragma unroll
      for (int j = 0; j < 4; ++j) {
        const int r = wn + j * 16 + (lane & 15);
        bf[j] = *(const short8*)(Bs + r * BK + (c ^ (r & 7)) * 8);
      }
#pragma unroll
      for (int i = 0; i < 4; ++i)
#pragma unroll
        for (int j = 0; j < 4; ++j)
          acc[i][j] = __builtin_amdgcn_mfma_f32_16x16x32_bf16(af[i], bf[j], acc[i][j], 0, 0, 0);
    }
  }

  // Epilogue: D[row=(lane>>4)*4+r][col=lane&15] per 16x16 frag (m89-verified layout).
  const int cn = lane & 15;
  const int rq = (lane >> 4) * 4;
#pragma unroll
  for (int j = 0; j < 4; ++j) {
    const int n = n0 + wn + j * 16 + cn;
    const float bv = bias[n];
#pragma unroll
    for (int i = 0; i < 4; ++i) {
      const long mb = (long)(m0 + wm + i * 16 + rq) * N_DIM + n;
#pragma unroll
      for (int r = 0; r < 4; ++r)
        C[mb + (long)r * N_DIM] = acc[i][j][r] + bv;
    }
  }
}

extern "C" void kernel_launch(void* const* d_in, const int* in_sizes, int n_in,
                              void* d_out, int out_size, void* d_ws, size_t ws_size,
                              hipStream_t stream) {
  const float* x = (const float*)d_in[0];      // [8,2048,1024]
  const float* theta = (const float*)d_in[1];  // [128,8] -> flat 1024
  const float* W = (const float*)d_in[2];      // [1024,1024]
  const float* b = (const float*)d_in[3];      // [1024]
  float* out = (float*)d_out;                  // [8,2048,1024] f32

  unsigned short* Abf = (unsigned short*)d_ws;                   // 33.5 MB
  unsigned short* Wbf = Abf + (size_t)M_DIM * K_DIM;             // +2 MB

  hipLaunchKernelGGL(prep_all, dim3(PREP_A_BLOCKS + PREP_W_BLOCKS), dim3(256), 0,
                     stream, x, theta, W, Abf, Wbf);
  hipLaunchKernelGGL(gemm_bt, dim3(N_DIM / 128, M_DIM / 128), dim3(256), 0, stream,
                     Abf, Wbf, b, out);
}